// Round 5
// baseline (366.026 us; speedup 1.0000x reference)
//
#include <hip/hip_runtime.h>

// ---------------------------------------------------------------------------
// MDNV2 fused kernels for MI355X (gfx950) — round 5
//
// vs round 4: pair_kernel is PERSISTENT. grid=256 (1 block/CU), each block
// owns nh-half (blockIdx&1) and 10 contiguous M-tiles of 256 rows.
//  * W2 half (114 KB, MFMA-fragment order) staged into LDS ONCE per block.
//  * Tile loop is BARRIER-FREE (LDS read-only after the single barrier):
//    8 waves drift independently -> cross-phase overlap (loads/MFMA/stores).
//  * acc initialized with bias (C-in), bias regs hoisted out of the loop.
//  * Contiguous tile runs -> Pq rows L2-resident across a block's tiles.
// ---------------------------------------------------------------------------

typedef __attribute__((ext_vector_type(8))) short bf16x8;
typedef __attribute__((ext_vector_type(4))) float f32x4;
typedef __attribute__((ext_vector_type(16))) float f32x16;
typedef __attribute__((ext_vector_type(4))) unsigned int u32x4;

#define M_TOT 327680

__device__ __forceinline__ unsigned short f2bf(float f) {
    union { float f; unsigned int u; } v; v.f = f;
    unsigned int r = (v.u + 0x7FFFu + ((v.u >> 16) & 1u)) >> 16;  // RNE
    return (unsigned short)r;
}

__device__ __forceinline__ float eluf(float y) {
    return fmaxf(y, 0.f) + __expf(fminf(y, 0.f)) - 1.f;
}

__device__ __forceinline__ unsigned packbf(float y0, float y1) {
    return (__float_as_uint(y1) & 0xFFFF0000u) | (__float_as_uint(y0) >> 16);
}

// ---------------------------------------------------------------------------
// prep_weights: ws layout (bytes):
//   W1T @0       : [256 n][256 k] bf16                              131072
//   W2s @131072  : packed [nh 2][fk 8][frag 7][c 4][n 32][j 8] bf16 229376
//   b2  @360448  : [448] f32 (pi@0, sig@144, mu@288, pads zero)
//   a1  @362240  : [256] f32
//   cs  @363264  : [256] f32
//   Lq  @364544  : [768][256] f32
//   Pq  @1150976 : [6144][256] f32
// W2s element (nh,fk,frag,c,n,j) = W2[k][nG],
//   k = fk*32 + (c>>1)*16 + (c&1)*8 + j,  nG = nh*224 + frag*32 + n.
// ---------------------------------------------------------------------------
__global__ void prep_weights(const float* __restrict__ W1, const float* __restrict__ b1,
                             const float* __restrict__ gamma, const float* __restrict__ beta,
                             const float* __restrict__ rmean, const float* __restrict__ rvar,
                             const float* __restrict__ Wpi, const float* __restrict__ bpi,
                             const float* __restrict__ Wsig, const float* __restrict__ bsig,
                             const float* __restrict__ Wmu, const float* __restrict__ bmu,
                             unsigned short* __restrict__ W1T, unsigned short* __restrict__ W2s,
                             float* __restrict__ b2, float* __restrict__ a1v, float* __restrict__ csv) {
    int idx = blockIdx.x * 256 + threadIdx.x;          // grid 448 -> 114688 threads
    {
        int j  = idx & 7;
        int n5 = (idx >> 3) & 31;
        int c  = (idx >> 8) & 3;
        int t  = idx >> 10;                            // 0..111
        int frag = t % 7;
        int t2   = t / 7;                              // 0..15
        int fk   = t2 & 7;
        int nh   = t2 >> 3;
        int k  = fk * 32 + ((c >> 1) << 4) + ((c & 1) << 3) + j;
        int nG = nh * 224 + frag * 32 + n5;
        float v = 0.f;
        if (nG < 140)                    v = Wpi [k * 140 + nG];
        else if (nG >= 144 && nG < 284)  v = Wsig[k * 140 + (nG - 144)];
        else if (nG >= 288 && nG < 428)  v = Wmu [k * 140 + (nG - 288)];
        W2s[idx] = f2bf(v);
    }
    if (idx < 256 * 256) {                             // W1T[n][k] = W1[k][n]
        int n = idx >> 8, k = idx & 255;
        W1T[idx] = f2bf(W1[k * 256 + n]);
    }
    if (idx < 448) {
        float v = 0.f;
        if (idx < 140)                      v = bpi [idx];
        else if (idx >= 144 && idx < 284)   v = bsig[idx - 144];
        else if (idx >= 288 && idx < 428)   v = bmu [idx - 288];
        b2[idx] = v;
    }
    if (idx < 256) {
        float s = gamma[idx] * rsqrtf(rvar[idx] + 1e-5f);
        a1v[idx] = s;
        csv[idx] = s * (b1[idx] - rmean[idx]) + beta[idx];
    }
}

// ---------------------------------------------------------------------------
// node_gemm: Lq (BN shift folded) / Pq (scale only) -- unchanged
// ---------------------------------------------------------------------------
__global__ __launch_bounds__(256, 2) void node_gemm(
        const float* __restrict__ h_l, const float* __restrict__ h_p,
        const unsigned short* __restrict__ W1T,
        const float* __restrict__ a1v, const float* __restrict__ csv,
        float* __restrict__ Lq, float* __restrict__ Pq) {
    const int tid = threadIdx.x, lane = tid & 63, w = tid >> 6;
    const int cGrp = lane & 15, g = lane >> 4;
    const int row0 = blockIdx.x * 64;
    const bool isLig = row0 < 768;
    const float* src = isLig ? (h_l + (size_t)row0 * 128) : (h_p + (size_t)(row0 - 768) * 128);
    float*       dst = isLig ? (Lq + (size_t)row0 * 256) : (Pq + (size_t)(row0 - 768) * 256);
    const int koff = isLig ? 0 : 128;

    f32x4 acc[16];
    #pragma unroll
    for (int fn = 0; fn < 16; ++fn) acc[fn] = (f32x4){0.f, 0.f, 0.f, 0.f};

    #pragma unroll
    for (int fk = 0; fk < 4; ++fk) {
        const float* ap = src + (size_t)(w * 16 + cGrp) * 128 + fk * 32 + g * 8;
        f32x4 qa = *(const f32x4*)ap;
        f32x4 qb = *(const f32x4*)(ap + 4);
        bf16x8 af;
        af[0] = (short)f2bf(qa[0]); af[1] = (short)f2bf(qa[1]);
        af[2] = (short)f2bf(qa[2]); af[3] = (short)f2bf(qa[3]);
        af[4] = (short)f2bf(qb[0]); af[5] = (short)f2bf(qb[1]);
        af[6] = (short)f2bf(qb[2]); af[7] = (short)f2bf(qb[3]);
        #pragma unroll
        for (int fn = 0; fn < 16; ++fn) {
            bf16x8 bf = *(const bf16x8*)(W1T + (fn * 16 + cGrp) * 256 + koff + fk * 32 + g * 8);
            acc[fn] = __builtin_amdgcn_mfma_f32_16x16x32_bf16(af, bf, acc[fn], 0, 0, 0);
        }
    }
    #pragma unroll
    for (int fn = 0; fn < 16; ++fn) {
        int h = fn * 16 + cGrp;
        float s = a1v[h];
        float c0 = isLig ? csv[h] : 0.f;
        #pragma unroll
        for (int rg = 0; rg < 4; ++rg)
            dst[(size_t)(w * 16 + g * 4 + rg) * 256 + h] = s * acc[fn][rg] + c0;
    }
}

// ---------------------------------------------------------------------------
// pair_kernel (persistent): grid 256, block 512.
//   block -> nh = blockIdx&1, 10 contiguous tiles starting at (blockIdx>>1)*10
// ---------------------------------------------------------------------------
__global__ __launch_bounds__(512, 2) void pair_kernel(
        const float* __restrict__ Lq, const float* __restrict__ Pq,
        const unsigned short* __restrict__ W2s, const float* __restrict__ b2p,
        const float* __restrict__ lig_pos, const float* __restrict__ prot_pos,
        float* __restrict__ out_pi, float* __restrict__ out_sig, float* __restrict__ out_mu,
        float* __restrict__ out_dist, float* __restrict__ out_pb) {

    __shared__ __align__(16) unsigned short Bs[57344];   // 114688 B, block lifetime

    const int tid = threadIdx.x, lane = tid & 63, w = tid >> 6;
    const int ln31 = lane & 31, hi = lane >> 5;
    const int nh = blockIdx.x & 1;
    const int bh = blockIdx.x >> 1;                      // 0..127

    // ---- stage weights once ----
    const unsigned short* wsrc = W2s + (size_t)nh * 57344;
    #pragma unroll
    for (int i = 0; i < 14; ++i)
        *(bf16x8*)(Bs + (size_t)(tid + 512 * i) * 8) =
            *(const bf16x8*)(wsrc + (size_t)(tid + 512 * i) * 8);

    // ---- bias regs (uniform across tiles) ----
    float bb[7];
    #pragma unroll
    for (int f = 0; f < 7; ++f) bb[f] = b2p[nh * 224 + f * 32 + ln31];

    __syncthreads();    // the ONLY barrier

    #pragma unroll 1
    for (int it = 0; it < 10; ++it) {
        const int tile = bh * 10 + it;
        const int m0 = tile * 256;

        // ---- closed-form pair decode ----
        unsigned int P = (unsigned int)m0 / 40960u;
        unsigned int r = (unsigned int)m0 % 40960u;
        int b, cl, cp0;
        if (r < 8192u) {
            b = 2 * (int)P; cl = 96 * (int)P + (int)(r >> 8); cp0 = 768 * (int)P;
        } else {
            unsigned int rr = r - 8192u;
            b = 2 * (int)P + 1; cl = 96 * (int)P + 32 + (int)(rr >> 9);
            cp0 = 768 * (int)P + 256 + (int)(rr & 511u);
        }

        // ---- X = elu(Lq[cl] + Pq[cp]) into registers (A-fragment layout) ----
        const int xrow = w * 32 + ln31;
        const float* pqp = Pq + (size_t)(cp0 + xrow) * 256 + hi * 8;
        const float* lqp = Lq + (size_t)cl * 256 + hi * 8;
        bf16x8 Xr[16];
        #pragma unroll
        for (int s = 0; s < 16; ++s) {
            f32x4 p0 = *(const f32x4*)(pqp + s * 16);
            f32x4 p1 = *(const f32x4*)(pqp + s * 16 + 4);
            f32x4 l0 = *(const f32x4*)(lqp + s * 16);
            f32x4 l1 = *(const f32x4*)(lqp + s * 16 + 4);
            float y0 = eluf(p0[0] + l0[0]), y1 = eluf(p0[1] + l0[1]);
            float y2 = eluf(p0[2] + l0[2]), y3 = eluf(p0[3] + l0[3]);
            float y4 = eluf(p1[0] + l1[0]), y5 = eluf(p1[1] + l1[1]);
            float y6 = eluf(p1[2] + l1[2]), y7 = eluf(p1[3] + l1[3]);
            union { u32x4 u; bf16x8 h; } cv;
            cv.u[0] = packbf(y0, y1); cv.u[1] = packbf(y2, y3);
            cv.u[2] = packbf(y4, y5); cv.u[3] = packbf(y6, y7);
            Xr[s] = cv.h;
        }

        // ---- K-loop: pure ds_read + MFMA (acc seeded with bias) ----
        f32x16 acc[7];
        #pragma unroll
        for (int f = 0; f < 7; ++f)
            #pragma unroll
            for (int q = 0; q < 16; ++q) acc[f][q] = bb[f];

        #pragma unroll
        for (int s = 0; s < 16; ++s) {
            const int base = (s >> 1) * 7168 + ((s & 1) * 2 + hi) * 256 + ln31 * 8;
            #pragma unroll
            for (int f = 0; f < 7; ++f) {
                bf16x8 bf = *(const bf16x8*)(Bs + base + f * 1024);
                acc[f] = __builtin_amdgcn_mfma_f32_32x32x16_bf16(Xr[s], bf, acc[f], 0, 0, 0);
            }
        }

        if (nh == 0) {
            // ---- pi softmax (cols 0..139), wave-local ----
            const bool v4 = (ln31 < 12);
            #pragma unroll
            for (int q = 0; q < 16; ++q) {
                float m01 = fmaxf(acc[0][q], acc[1][q]);
                float m23 = fmaxf(acc[2][q], acc[3][q]);
                float mx = fmaxf(fmaxf(m01, m23), v4 ? acc[4][q] : -3.0e38f);
                #pragma unroll
                for (int d = 1; d < 32; d <<= 1) mx = fmaxf(mx, __shfl_xor(mx, d, 64));
                float e0 = __expf(acc[0][q] - mx), e1 = __expf(acc[1][q] - mx);
                float e2 = __expf(acc[2][q] - mx), e3 = __expf(acc[3][q] - mx);
                float e4 = v4 ? __expf(acc[4][q] - mx) : 0.f;
                float sm = e0 + e1 + e2 + e3 + e4;
                #pragma unroll
                for (int d = 1; d < 32; d <<= 1) sm += __shfl_xor(sm, d, 64);
                float inv = 1.f / sm;
                acc[0][q] = e0 * inv; acc[1][q] = e1 * inv;
                acc[2][q] = e2 * inv; acc[3][q] = e3 * inv;
                if (v4) acc[4][q] = e4 * inv;
            }
            #pragma unroll
            for (int q = 0; q < 16; ++q) {
                const int gr = m0 + w * 32 + (q & 3) + 8 * (q >> 2) + 4 * hi;
                float* prow = out_pi + (size_t)gr * 140;
                prow[ln31]       = acc[0][q];
                prow[32 + ln31]  = acc[1][q];
                prow[64 + ln31]  = acc[2][q];
                prow[96 + ln31]  = acc[3][q];
                if (v4) prow[128 + ln31] = acc[4][q];
                float* srow = out_sig + (size_t)gr * 140;
                if (ln31 >= 16) srow[ln31 - 16] = eluf(acc[4][q]) + 1.1f;
                srow[16 + ln31] = eluf(acc[5][q]) + 1.1f;
                srow[48 + ln31] = eluf(acc[6][q]) + 1.1f;
            }
        } else {
            #pragma unroll
            for (int q = 0; q < 16; ++q) {
                const int gr = m0 + w * 32 + (q & 3) + 8 * (q >> 2) + 4 * hi;
                float* srow = out_sig + (size_t)gr * 140;
                srow[80 + ln31] = eluf(acc[0][q]) + 1.1f;
                if (ln31 < 28) srow[112 + ln31] = eluf(acc[1][q]) + 1.1f;
                float* mrow = out_mu + (size_t)gr * 140;
                mrow[ln31]      = eluf(acc[2][q]) + 1.0f;
                mrow[32 + ln31] = eluf(acc[3][q]) + 1.0f;
                mrow[64 + ln31] = eluf(acc[4][q]) + 1.0f;
                mrow[96 + ln31] = eluf(acc[5][q]) + 1.0f;
                if (ln31 < 12) mrow[128 + ln31] = eluf(acc[6][q]) + 1.0f;
            }
            // ---- dist + pb (nh=1 only) ----
            float lx = lig_pos[cl * 3 + 0];
            float ly = lig_pos[cl * 3 + 1];
            float lz = lig_pos[cl * 3 + 2];
            #pragma unroll
            for (int i = 0; i < 7; ++i) {
                int idx = tid + 512 * i;                  // < 3584
                int rw = idx / 14, a = idx - rw * 14;
                const float* pp = prot_pos + (size_t)(cp0 + rw) * 42 + a * 3;
                float dx = lx - pp[0], dy = ly - pp[1], dz = lz - pp[2];
                out_dist[(size_t)(m0 + rw) * 14 + a] = sqrtf(dx * dx + dy * dy + dz * dz);
            }
            if (tid < 256) out_pb[m0 + tid] = (float)b;
        }
    }
}

// ---------------------------------------------------------------------------
// Tail: atom_types [768,17] and bond_types [2048,5]
// ---------------------------------------------------------------------------
__global__ void tail_kernel(const float* __restrict__ h_l,
                            const int* __restrict__ esrc, const int* __restrict__ edst,
                            const float* __restrict__ Wat, const float* __restrict__ bat,
                            const float* __restrict__ Wbt, const float* __restrict__ bbt,
                            float* __restrict__ out_at, float* __restrict__ out_bt) {
    int t = blockIdx.x * 256 + threadIdx.x;
    if (t < 768 * 17) {
        int row = t / 17, c = t % 17;
        const float* hr = h_l + (size_t)row * 128;
        float s = bat[c];
        #pragma unroll 4
        for (int k = 0; k < 128; ++k) s += hr[k] * Wat[k * 17 + c];
        out_at[t] = s;
    } else {
        int t2 = t - 768 * 17;
        if (t2 < 2048 * 5) {
            int e = t2 / 5, c = t2 % 5;
            const float* hs = h_l + (size_t)esrc[e] * 128;
            const float* hd = h_l + (size_t)edst[e] * 128;
            float s = bbt[c];
            #pragma unroll 4
            for (int k = 0; k < 128; ++k)
                s += hs[k] * Wbt[k * 5 + c] + hd[k] * Wbt[(k + 128) * 5 + c];
            out_bt[t2] = s;
        }
    }
}

// ---------------------------------------------------------------------------
extern "C" void kernel_launch(void* const* d_in, const int* in_sizes, int n_in,
                              void* d_out, int out_size, void* d_ws, size_t ws_size,
                              hipStream_t stream) {
    const float* h_l      = (const float*)d_in[0];
    const float* h_p      = (const float*)d_in[1];
    const float* lig_pos  = (const float*)d_in[2];
    const float* prot_pos = (const float*)d_in[3];
    const int*   esrc     = (const int*)d_in[4];
    const int*   edst     = (const int*)d_in[5];
    const float* W1    = (const float*)d_in[12];
    const float* b1    = (const float*)d_in[13];
    const float* gamma = (const float*)d_in[14];
    const float* beta  = (const float*)d_in[15];
    const float* rmean = (const float*)d_in[16];
    const float* rvar  = (const float*)d_in[17];
    const float* Wpi   = (const float*)d_in[18];
    const float* bpi   = (const float*)d_in[19];
    const float* Wsig  = (const float*)d_in[20];
    const float* bsig  = (const float*)d_in[21];
    const float* Wmu   = (const float*)d_in[22];
    const float* bmu   = (const float*)d_in[23];
    const float* Wat   = (const float*)d_in[24];
    const float* bat   = (const float*)d_in[25];
    const float* Wbt   = (const float*)d_in[26];
    const float* bbt   = (const float*)d_in[27];

    char* ws = (char*)d_ws;
    unsigned short* W1T = (unsigned short*)(ws + 0);
    unsigned short* W2s = (unsigned short*)(ws + 131072);
    float*          b2  = (float*)(ws + 360448);
    float*          a1v = (float*)(ws + 362240);
    float*          csv = (float*)(ws + 363264);
    float*          Lq  = (float*)(ws + 364544);
    float*          Pq  = (float*)(ws + 1150976);

    float* out = (float*)d_out;
    const size_t M = M_TOT;
    float* out_pi   = out;
    float* out_sig  = out + M * 140;
    float* out_mu   = out + 2 * M * 140;
    float* out_dist = out + 3 * M * 140;
    float* out_at   = out + 3 * M * 140 + M * 14;
    float* out_bt   = out_at + 768 * 17;
    float* out_pb   = out_bt + 2048 * 5;

    hipLaunchKernelGGL(prep_weights, dim3(448), dim3(256), 0, stream,
                       W1, b1, gamma, beta, rmean, rvar,
                       Wpi, bpi, Wsig, bsig, Wmu, bmu,
                       W1T, W2s, b2, a1v, csv);

    hipLaunchKernelGGL(node_gemm, dim3((768 + 6144) / 64), dim3(256), 0, stream,
                       h_l, h_p, W1T, a1v, csv, Lq, Pq);

    hipLaunchKernelGGL(pair_kernel, dim3(256), dim3(512), 0, stream,
                       Lq, Pq, W2s, b2, lig_pos, prot_pos,
                       out_pi, out_sig, out_mu, out_dist, out_pb);

    hipLaunchKernelGGL(tail_kernel, dim3((768 * 17 + 2048 * 5 + 255) / 256), dim3(256), 0, stream,
                       h_l, esrc, edst, Wat, bat, Wbt, bbt, out_at, out_bt);
}

// Round 6
// 242.472 us; speedup vs baseline: 1.5096x; 1.5096x over previous
//
#include <hip/hip_runtime.h>

// ---------------------------------------------------------------------------
// MDNV2 fused kernels for MI355X (gfx950) — round 6
//
// vs round 5: GEMM2 in fp8 (e4m3, weights pre-scaled x16, HW cvt_pk_fp8),
// halving LDS footprint (57 KB -> 2 blocks/CU) and operand registers
// (VGPR<=128 -> 4 waves/SIMD). Lq/Pq stored bf16 (Pq 3 MB = L2-resident).
// M-tile 128, wave = 16 rows x 224 cols (14 x 16-col frags), grid (2560,2).
// B-frags packed lane-sequential in LDS -> conflict-free ds_read_b128.
// ---------------------------------------------------------------------------

typedef __attribute__((ext_vector_type(4))) float f32x4;
typedef __attribute__((ext_vector_type(4))) unsigned int u32x4;

#define M_TOT 327680
#define WSCALE 16.0f
#define WDESCALE 0.0625f

__device__ __forceinline__ unsigned short f2bf(float f) {
    union { float f; unsigned int u; } v; v.f = f;
    unsigned int r = (v.u + 0x7FFFu + ((v.u >> 16) & 1u)) >> 16;  // RNE
    return (unsigned short)r;
}

__device__ __forceinline__ float eluf(float y) {
    return fmaxf(y, 0.f) + __expf(fminf(y, 0.f)) - 1.f;
}

__device__ __forceinline__ float bfhalf_lo(unsigned int u) {
    return __uint_as_float(u << 16);
}
__device__ __forceinline__ float bfhalf_hi(unsigned int u) {
    return __uint_as_float(u & 0xFFFF0000u);
}

// ---------------------------------------------------------------------------
// prep_weights: ws layout (bytes):
//   W1T @0      : [256 n][256 k] bf16                                131072
//   W2q @131072 : fp8 [nh 2][f 14][sp 4][lane 64][h 2][j 8]          114688
//   b2s @245760 : [448] f32  (bias x 16; padded-col slots zero)
//   a1  @247552 : [256] f32
//   cs  @248576 : [256] f32
//   Lq  @249600 : [768][256] bf16
//   Pq  @642816 : [6144][256] bf16   (3 MB -> L2-resident per XCD)
// W2q element (nh,f,sp,lane,h,j) = 16*W2[k][col],
//   k = (sp*2+h)*32 + (lane>>4)*8 + j,  col = nh*224 + f*16 + (lane&15)
// ---------------------------------------------------------------------------
__global__ void prep_weights(const float* __restrict__ W1, const float* __restrict__ b1,
                             const float* __restrict__ gamma, const float* __restrict__ beta,
                             const float* __restrict__ rmean, const float* __restrict__ rvar,
                             const float* __restrict__ Wpi, const float* __restrict__ bpi,
                             const float* __restrict__ Wsig, const float* __restrict__ bsig,
                             const float* __restrict__ Wmu, const float* __restrict__ bmu,
                             unsigned short* __restrict__ W1T, unsigned char* __restrict__ W2q,
                             float* __restrict__ b2s, float* __restrict__ a1v, float* __restrict__ csv) {
    int idx = blockIdx.x * 256 + threadIdx.x;          // 448 blocks -> 114688
    {
        int j    = idx & 7;
        int h    = (idx >> 3) & 1;
        int lane = (idx >> 4) & 63;
        int sp   = (idx >> 10) & 3;
        int t    = idx >> 12;                          // 0..27
        int f    = t % 14;
        int nhq  = t / 14;
        int k    = (sp * 2 + h) * 32 + (lane >> 4) * 8 + j;
        int col  = nhq * 224 + f * 16 + (lane & 15);
        float v = 0.f;
        if (col < 140)                    v = Wpi [k * 140 + col];
        else if (col >= 144 && col < 284) v = Wsig[k * 140 + (col - 144)];
        else if (col >= 288 && col < 428) v = Wmu [k * 140 + (col - 288)];
        v *= WSCALE;
        W2q[idx] = (unsigned char)(__builtin_amdgcn_cvt_pk_fp8_f32(v, 0.f, 0, false) & 0xFF);
    }
    if (idx < 256 * 256) {                             // W1T[n][k] = W1[k][n]
        int n = idx >> 8, k = idx & 255;
        W1T[idx] = f2bf(W1[k * 256 + n]);
    }
    if (idx < 448) {
        float v = 0.f;
        if (idx < 140)                      v = bpi [idx];
        else if (idx >= 144 && idx < 284)   v = bsig[idx - 144];
        else if (idx >= 288 && idx < 428)   v = bmu [idx - 288];
        b2s[idx] = v * WSCALE;
    }
    if (idx < 256) {
        float s = gamma[idx] * rsqrtf(rvar[idx] + 1e-5f);
        a1v[idx] = s;
        csv[idx] = s * (b1[idx] - rmean[idx]) + beta[idx];
    }
}

// ---------------------------------------------------------------------------
// node_gemm: Lq (BN shift folded) / Pq (scale only), bf16 output
// ---------------------------------------------------------------------------
typedef __attribute__((ext_vector_type(8))) short bf16x8;

__global__ __launch_bounds__(256, 2) void node_gemm(
        const float* __restrict__ h_l, const float* __restrict__ h_p,
        const unsigned short* __restrict__ W1T,
        const float* __restrict__ a1v, const float* __restrict__ csv,
        unsigned short* __restrict__ Lq, unsigned short* __restrict__ Pq) {
    const int tid = threadIdx.x, lane = tid & 63, w = tid >> 6;
    const int cGrp = lane & 15, g = lane >> 4;
    const int row0 = blockIdx.x * 64;
    const bool isLig = row0 < 768;
    const float* src = isLig ? (h_l + (size_t)row0 * 128) : (h_p + (size_t)(row0 - 768) * 128);
    unsigned short* dst = isLig ? (Lq + (size_t)row0 * 256) : (Pq + (size_t)(row0 - 768) * 256);
    const int koff = isLig ? 0 : 128;

    f32x4 acc[16];
    #pragma unroll
    for (int fn = 0; fn < 16; ++fn) acc[fn] = (f32x4){0.f, 0.f, 0.f, 0.f};

    #pragma unroll
    for (int fk = 0; fk < 4; ++fk) {
        const float* ap = src + (size_t)(w * 16 + cGrp) * 128 + fk * 32 + g * 8;
        f32x4 qa = *(const f32x4*)ap;
        f32x4 qb = *(const f32x4*)(ap + 4);
        bf16x8 af;
        af[0] = (short)f2bf(qa[0]); af[1] = (short)f2bf(qa[1]);
        af[2] = (short)f2bf(qa[2]); af[3] = (short)f2bf(qa[3]);
        af[4] = (short)f2bf(qb[0]); af[5] = (short)f2bf(qb[1]);
        af[6] = (short)f2bf(qb[2]); af[7] = (short)f2bf(qb[3]);
        #pragma unroll
        for (int fn = 0; fn < 16; ++fn) {
            bf16x8 bf = *(const bf16x8*)(W1T + (fn * 16 + cGrp) * 256 + koff + fk * 32 + g * 8);
            acc[fn] = __builtin_amdgcn_mfma_f32_16x16x32_bf16(af, bf, acc[fn], 0, 0, 0);
        }
    }
    #pragma unroll
    for (int fn = 0; fn < 16; ++fn) {
        int h = fn * 16 + cGrp;
        float s = a1v[h];
        float c0 = isLig ? csv[h] : 0.f;
        #pragma unroll
        for (int rg = 0; rg < 4; ++rg)
            dst[(size_t)(w * 16 + g * 4 + rg) * 256 + h] = f2bf(s * acc[fn][rg] + c0);
    }
}

// ---------------------------------------------------------------------------
// pair_kernel: grid (2560, 2), block 512 (8 waves). Tile = 128 rows x 224 cols.
// Wave = 16 rows x 224 cols: acc 14 x f32x4 = 56 VGPR, Xa 8 x i64 = 16 VGPR.
// ---------------------------------------------------------------------------
__global__ __launch_bounds__(512, 4) void pair_kernel(
        const unsigned short* __restrict__ Lq, const unsigned short* __restrict__ Pq,
        const unsigned char* __restrict__ W2q, const float* __restrict__ b2s,
        const float* __restrict__ lig_pos, const float* __restrict__ prot_pos,
        float* __restrict__ out_pi, float* __restrict__ out_sig, float* __restrict__ out_mu,
        float* __restrict__ out_dist, float* __restrict__ out_pb) {

    __shared__ __align__(16) unsigned char Bs[57344];

    const int tid = threadIdx.x, lane = tid & 63, w = tid >> 6;
    const int c = lane & 15, g = lane >> 4;
    const int nh = blockIdx.y;
    const int m0 = blockIdx.x * 128;

    // ---- closed-form pair decode (tile within one batch+ligand run) ----
    unsigned int P = (unsigned int)m0 / 40960u;
    unsigned int r = (unsigned int)m0 % 40960u;
    int b, cl, cp0;
    if (r < 8192u) {            // even batch: 32 lig x 256 prot
        b = 2 * (int)P; cl = 96 * (int)P + (int)(r >> 8); cp0 = 768 * (int)P + (int)(r & 255u);
    } else {                    // odd batch: 64 lig x 512 prot
        unsigned int rr = r - 8192u;
        b = 2 * (int)P + 1; cl = 96 * (int)P + 32 + (int)(rr >> 9);
        cp0 = 768 * (int)P + 256 + (int)(rr & 511u);
    }

    // ---- issue weight staging loads (7 x 16B/thread) ----
    const unsigned char* wsrc = W2q + (size_t)nh * 57344;
    u32x4 stg[7];
    #pragma unroll
    for (int i = 0; i < 7; ++i)
        stg[i] = *(const u32x4*)(wsrc + (size_t)(tid + 512 * i) * 16);

    // ---- bias (x16 prescaled) ----
    float bb[14];
    #pragma unroll
    for (int f = 0; f < 14; ++f) bb[f] = b2s[nh * 224 + f * 16 + c];

    // ---- X = fp8(elu(Lq+Pq)) in registers (A-fragment layout) ----
    const int row = w * 16 + c;
    const unsigned short* pqp = Pq + (size_t)(cp0 + row) * 256;
    const unsigned short* lqp = Lq + (size_t)cl * 256;
    long Xa[8];
    #pragma unroll
    for (int s = 0; s < 8; ++s) {
        u32x4 pv = *(const u32x4*)(pqp + s * 32 + g * 8);
        u32x4 lv = *(const u32x4*)(lqp + s * 32 + g * 8);
        float y0 = eluf(bfhalf_lo(pv[0]) + bfhalf_lo(lv[0]));
        float y1 = eluf(bfhalf_hi(pv[0]) + bfhalf_hi(lv[0]));
        float y2 = eluf(bfhalf_lo(pv[1]) + bfhalf_lo(lv[1]));
        float y3 = eluf(bfhalf_hi(pv[1]) + bfhalf_hi(lv[1]));
        float y4 = eluf(bfhalf_lo(pv[2]) + bfhalf_lo(lv[2]));
        float y5 = eluf(bfhalf_hi(pv[2]) + bfhalf_hi(lv[2]));
        float y6 = eluf(bfhalf_lo(pv[3]) + bfhalf_lo(lv[3]));
        float y7 = eluf(bfhalf_hi(pv[3]) + bfhalf_hi(lv[3]));
        unsigned int lo = (unsigned int)__builtin_amdgcn_cvt_pk_fp8_f32(y0, y1, 0, false);
        lo = (unsigned int)__builtin_amdgcn_cvt_pk_fp8_f32(y2, y3, (int)lo, true);
        unsigned int hi = (unsigned int)__builtin_amdgcn_cvt_pk_fp8_f32(y4, y5, 0, false);
        hi = (unsigned int)__builtin_amdgcn_cvt_pk_fp8_f32(y6, y7, (int)hi, true);
        Xa[s] = (long)(((unsigned long long)hi << 32) | (unsigned long long)lo);
    }

    // ---- write staged weights to LDS, single barrier ----
    #pragma unroll
    for (int i = 0; i < 7; ++i)
        *(u32x4*)(Bs + (size_t)(tid + 512 * i) * 16) = stg[i];
    __syncthreads();

    // ---- K-loop: 56 conflict-free ds_read_b128 + 112 fp8 MFMA ----
    f32x4 acc[14];
    #pragma unroll
    for (int f = 0; f < 14; ++f) acc[f] = (f32x4){bb[f], bb[f], bb[f], bb[f]};

    #pragma unroll
    for (int sp = 0; sp < 4; ++sp) {
        long xa0 = Xa[2 * sp], xa1 = Xa[2 * sp + 1];
        #pragma unroll
        for (int f = 0; f < 14; ++f) {
            u32x4 bq = *(const u32x4*)(Bs + f * 4096 + sp * 1024 + lane * 16);
            long b0 = (long)(((unsigned long long)bq[1] << 32) | (unsigned long long)bq[0]);
            long b1 = (long)(((unsigned long long)bq[3] << 32) | (unsigned long long)bq[2]);
            acc[f] = __builtin_amdgcn_mfma_f32_16x16x32_fp8_fp8(xa0, b0, acc[f], 0, 0, 0);
            acc[f] = __builtin_amdgcn_mfma_f32_16x16x32_fp8_fp8(xa1, b1, acc[f], 0, 0, 0);
        }
    }

    // ---- de-scale ----
    #pragma unroll
    for (int f = 0; f < 14; ++f)
        #pragma unroll
        for (int q = 0; q < 4; ++q) acc[f][q] *= WDESCALE;

    if (nh == 0) {
        // pi cols 0..139 (f0..8), sig cols 0..79 (f9..13); softmax 16-lane local
        const bool v8 = (c < 12);
        #pragma unroll
        for (int q = 0; q < 4; ++q) {
            float mx = fmaxf(fmaxf(fmaxf(acc[0][q], acc[1][q]), fmaxf(acc[2][q], acc[3][q])),
                             fmaxf(fmaxf(acc[4][q], acc[5][q]), fmaxf(acc[6][q], acc[7][q])));
            if (v8) mx = fmaxf(mx, acc[8][q]);
            mx = fmaxf(mx, __shfl_xor(mx, 1, 64));
            mx = fmaxf(mx, __shfl_xor(mx, 2, 64));
            mx = fmaxf(mx, __shfl_xor(mx, 4, 64));
            mx = fmaxf(mx, __shfl_xor(mx, 8, 64));
            float e0 = __expf(acc[0][q] - mx), e1 = __expf(acc[1][q] - mx);
            float e2 = __expf(acc[2][q] - mx), e3 = __expf(acc[3][q] - mx);
            float e4 = __expf(acc[4][q] - mx), e5 = __expf(acc[5][q] - mx);
            float e6 = __expf(acc[6][q] - mx), e7 = __expf(acc[7][q] - mx);
            float e8 = v8 ? __expf(acc[8][q] - mx) : 0.f;
            float sm = ((e0 + e1) + (e2 + e3)) + ((e4 + e5) + (e6 + e7)) + e8;
            sm += __shfl_xor(sm, 1, 64);
            sm += __shfl_xor(sm, 2, 64);
            sm += __shfl_xor(sm, 4, 64);
            sm += __shfl_xor(sm, 8, 64);
            float inv = 1.f / sm;
            const int gr = m0 + w * 16 + g * 4 + q;
            float* prow = out_pi + (size_t)gr * 140;
            prow[c]       = e0 * inv;  prow[16 + c]  = e1 * inv;
            prow[32 + c]  = e2 * inv;  prow[48 + c]  = e3 * inv;
            prow[64 + c]  = e4 * inv;  prow[80 + c]  = e5 * inv;
            prow[96 + c]  = e6 * inv;  prow[112 + c] = e7 * inv;
            if (v8) prow[128 + c] = e8 * inv;
            float* srow = out_sig + (size_t)gr * 140;
            srow[c]       = eluf(acc[9][q])  + 1.1f;
            srow[16 + c]  = eluf(acc[10][q]) + 1.1f;
            srow[32 + c]  = eluf(acc[11][q]) + 1.1f;
            srow[48 + c]  = eluf(acc[12][q]) + 1.1f;
            srow[64 + c]  = eluf(acc[13][q]) + 1.1f;
        }
    } else {
        // sig cols 80..139 (f0..3), mu cols 0..139 (f4..12), f13 = pad
        const bool v12 = (c < 12);
        #pragma unroll
        for (int q = 0; q < 4; ++q) {
            const int gr = m0 + w * 16 + g * 4 + q;
            float* srow = out_sig + (size_t)gr * 140;
            srow[80 + c]  = eluf(acc[0][q]) + 1.1f;
            srow[96 + c]  = eluf(acc[1][q]) + 1.1f;
            srow[112 + c] = eluf(acc[2][q]) + 1.1f;
            if (v12) srow[128 + c] = eluf(acc[3][q]) + 1.1f;
            float* mrow = out_mu + (size_t)gr * 140;
            mrow[c]       = eluf(acc[4][q])  + 1.0f;
            mrow[16 + c]  = eluf(acc[5][q])  + 1.0f;
            mrow[32 + c]  = eluf(acc[6][q])  + 1.0f;
            mrow[48 + c]  = eluf(acc[7][q])  + 1.0f;
            mrow[64 + c]  = eluf(acc[8][q])  + 1.0f;
            mrow[80 + c]  = eluf(acc[9][q])  + 1.0f;
            mrow[96 + c]  = eluf(acc[10][q]) + 1.0f;
            mrow[112 + c] = eluf(acc[11][q]) + 1.0f;
            if (v12) mrow[128 + c] = eluf(acc[12][q]) + 1.0f;
        }
        // ---- dist + pb (nh=1 blocks only) ----
        float lx = lig_pos[cl * 3 + 0];
        float ly = lig_pos[cl * 3 + 1];
        float lz = lig_pos[cl * 3 + 2];
        for (int idx = tid; idx < 128 * 14; idx += 512) {
            int rw = idx / 14, a = idx - rw * 14;
            const float* pp = prot_pos + (size_t)(cp0 + rw) * 42 + a * 3;
            float dx = lx - pp[0], dy = ly - pp[1], dz = lz - pp[2];
            out_dist[(size_t)(m0 + rw) * 14 + a] = sqrtf(dx * dx + dy * dy + dz * dz);
        }
        if (tid < 128) out_pb[m0 + tid] = (float)b;
    }
}

// ---------------------------------------------------------------------------
// Tail: atom_types [768,17] and bond_types [2048,5]
// ---------------------------------------------------------------------------
__global__ void tail_kernel(const float* __restrict__ h_l,
                            const int* __restrict__ esrc, const int* __restrict__ edst,
                            const float* __restrict__ Wat, const float* __restrict__ bat,
                            const float* __restrict__ Wbt, const float* __restrict__ bbt,
                            float* __restrict__ out_at, float* __restrict__ out_bt) {
    int t = blockIdx.x * 256 + threadIdx.x;
    if (t < 768 * 17) {
        int row = t / 17, c = t % 17;
        const float* hr = h_l + (size_t)row * 128;
        float s = bat[c];
        #pragma unroll 4
        for (int k = 0; k < 128; ++k) s += hr[k] * Wat[k * 17 + c];
        out_at[t] = s;
    } else {
        int t2 = t - 768 * 17;
        if (t2 < 2048 * 5) {
            int e = t2 / 5, c = t2 % 5;
            const float* hs = h_l + (size_t)esrc[e] * 128;
            const float* hd = h_l + (size_t)edst[e] * 128;
            float s = bbt[c];
            #pragma unroll 4
            for (int k = 0; k < 128; ++k)
                s += hs[k] * Wbt[k * 5 + c] + hd[k] * Wbt[(k + 128) * 5 + c];
            out_bt[t2] = s;
        }
    }
}

// ---------------------------------------------------------------------------
extern "C" void kernel_launch(void* const* d_in, const int* in_sizes, int n_in,
                              void* d_out, int out_size, void* d_ws, size_t ws_size,
                              hipStream_t stream) {
    const float* h_l      = (const float*)d_in[0];
    const float* h_p      = (const float*)d_in[1];
    const float* lig_pos  = (const float*)d_in[2];
    const float* prot_pos = (const float*)d_in[3];
    const int*   esrc     = (const int*)d_in[4];
    const int*   edst     = (const int*)d_in[5];
    const float* W1    = (const float*)d_in[12];
    const float* b1    = (const float*)d_in[13];
    const float* gamma = (const float*)d_in[14];
    const float* beta  = (const float*)d_in[15];
    const float* rmean = (const float*)d_in[16];
    const float* rvar  = (const float*)d_in[17];
    const float* Wpi   = (const float*)d_in[18];
    const float* bpi   = (const float*)d_in[19];
    const float* Wsig  = (const float*)d_in[20];
    const float* bsig  = (const float*)d_in[21];
    const float* Wmu   = (const float*)d_in[22];
    const float* bmu   = (const float*)d_in[23];
    const float* Wat   = (const float*)d_in[24];
    const float* bat   = (const float*)d_in[25];
    const float* Wbt   = (const float*)d_in[26];
    const float* bbt   = (const float*)d_in[27];

    char* ws = (char*)d_ws;
    unsigned short* W1T = (unsigned short*)(ws + 0);
    unsigned char*  W2q = (unsigned char*)(ws + 131072);
    float*          b2s = (float*)(ws + 245760);
    float*          a1v = (float*)(ws + 247552);
    float*          csv = (float*)(ws + 248576);
    unsigned short* Lq  = (unsigned short*)(ws + 249600);
    unsigned short* Pq  = (unsigned short*)(ws + 642816);

    float* out = (float*)d_out;
    const size_t M = M_TOT;
    float* out_pi   = out;
    float* out_sig  = out + M * 140;
    float* out_mu   = out + 2 * M * 140;
    float* out_dist = out + 3 * M * 140;
    float* out_at   = out + 3 * M * 140 + M * 14;
    float* out_bt   = out_at + 768 * 17;
    float* out_pb   = out_bt + 2048 * 5;

    hipLaunchKernelGGL(prep_weights, dim3(448), dim3(256), 0, stream,
                       W1, b1, gamma, beta, rmean, rvar,
                       Wpi, bpi, Wsig, bsig, Wmu, bmu,
                       W1T, W2q, b2s, a1v, csv);

    hipLaunchKernelGGL(node_gemm, dim3((768 + 6144) / 64), dim3(256), 0, stream,
                       h_l, h_p, W1T, a1v, csv, Lq, Pq);

    hipLaunchKernelGGL(pair_kernel, dim3(M_TOT / 128, 2), dim3(512), 0, stream,
                       Lq, Pq, W2q, b2s, lig_pos, prot_pos,
                       out_pi, out_sig, out_mu, out_dist, out_pb);

    hipLaunchKernelGGL(tail_kernel, dim3((768 * 17 + 2048 * 5 + 255) / 256), dim3(256), 0, stream,
                       h_l, esrc, edst, Wat, bat, Wbt, bbt, out_at, out_bt);
}

// Round 7
// 207.081 us; speedup vs baseline: 1.7676x; 1.1709x over previous
//
#include <hip/hip_runtime.h>

// ---------------------------------------------------------------------------
// MDNV2 fused kernels for MI355X (gfx950) — round 7
//
// vs round 6: N split by HEAD (pi/sig/mu, 144 cols each) instead of halves.
//  * Block = 256 thr (4 waves), tile 64 rows x 144 cols, LDS 36.9 KB
//    -> 4 co-resident blocks/CU (matches 16-wave reg cap) for smooth
//    cross-phase overlap of loads / MFMA / stores.
//  * pi softmax wave-local in head-0 blocks; sig/mu rows single-writer.
//  * tail (atom/bond types) folded into prep_weights.
// fp8 e4m3 GEMM2 (weights x16), bf16 Lq/Pq (L2-resident) as round 6.
// ---------------------------------------------------------------------------

typedef __attribute__((ext_vector_type(4))) float f32x4;
typedef __attribute__((ext_vector_type(4))) unsigned int u32x4;
typedef __attribute__((ext_vector_type(8))) short bf16x8;

#define M_TOT 327680
#define WSCALE 16.0f
#define WDESCALE 0.0625f

__device__ __forceinline__ unsigned short f2bf(float f) {
    union { float f; unsigned int u; } v; v.f = f;
    unsigned int r = (v.u + 0x7FFFu + ((v.u >> 16) & 1u)) >> 16;  // RNE
    return (unsigned short)r;
}

__device__ __forceinline__ float eluf(float y) {
    return fmaxf(y, 0.f) + __expf(fminf(y, 0.f)) - 1.f;
}

__device__ __forceinline__ float bfhalf_lo(unsigned int u) {
    return __uint_as_float(u << 16);
}
__device__ __forceinline__ float bfhalf_hi(unsigned int u) {
    return __uint_as_float(u & 0xFFFF0000u);
}

// ---------------------------------------------------------------------------
// prep_weights (+ folded tail): ws layout (bytes):
//   W1T @0      : [256 n][256 k] bf16                                131072
//   W2q @131072 : fp8 [head 3][f 9][sp 4][lane 64][h 2][j 8]         110592
//   b2s @241664 : [3][144] f32 (bias x16, pads zero)                   1728
//   a1  @243392 : [256] f32
//   cs  @244416 : [256] f32
//   Lq  @245440 : [768][256] bf16
//   Pq  @638656 : [6144][256] bf16  (3 MB -> L2-resident)
// W2q element (head,f,sp,lane,h,j) = 16*Whead[k][col],
//   k = (sp*2+h)*32 + (lane>>4)*8 + j,  col = f*16 + (lane&15)  (0 if >=140)
// ---------------------------------------------------------------------------
__global__ void prep_weights(const float* __restrict__ W1, const float* __restrict__ b1,
                             const float* __restrict__ gamma, const float* __restrict__ beta,
                             const float* __restrict__ rmean, const float* __restrict__ rvar,
                             const float* __restrict__ Wpi, const float* __restrict__ bpi,
                             const float* __restrict__ Wsig, const float* __restrict__ bsig,
                             const float* __restrict__ Wmu, const float* __restrict__ bmu,
                             const float* __restrict__ h_l,
                             const int* __restrict__ esrc, const int* __restrict__ edst,
                             const float* __restrict__ Wat, const float* __restrict__ bat,
                             const float* __restrict__ Wbt, const float* __restrict__ bbt,
                             unsigned short* __restrict__ W1T, unsigned char* __restrict__ W2q,
                             float* __restrict__ b2s, float* __restrict__ a1v, float* __restrict__ csv,
                             float* __restrict__ out_at, float* __restrict__ out_bt) {
    int idx = blockIdx.x * 256 + threadIdx.x;          // 432 blocks -> 110592
    {
        int j    = idx & 7;
        int h    = (idx >> 3) & 1;
        int lane = (idx >> 4) & 63;
        int sp   = (idx >> 10) & 3;
        int t    = idx >> 12;                          // 0..26
        int f    = t % 9;
        int head = t / 9;
        int k    = (sp * 2 + h) * 32 + (lane >> 4) * 8 + j;
        int col  = f * 16 + (lane & 15);
        float v = 0.f;
        if (col < 140) {
            const float* Wh = (head == 0) ? Wpi : (head == 1) ? Wsig : Wmu;
            v = Wh[k * 140 + col] * WSCALE;
        }
        W2q[idx] = (unsigned char)(__builtin_amdgcn_cvt_pk_fp8_f32(v, 0.f, 0, false) & 0xFF);
    }
    if (idx < 256 * 256) {                             // W1T[n][k] = W1[k][n]
        int n = idx >> 8, k = idx & 255;
        W1T[idx] = f2bf(W1[k * 256 + n]);
    }
    if (idx < 432) {                                   // b2s[head][col]
        int head = idx / 144, col = idx % 144;
        float v = 0.f;
        if (col < 140) v = (head == 0) ? bpi[col] : (head == 1) ? bsig[col] : bmu[col];
        b2s[idx] = v * WSCALE;
    }
    if (idx < 256) {
        float s = gamma[idx] * rsqrtf(rvar[idx] + 1e-5f);
        a1v[idx] = s;
        csv[idx] = s * (b1[idx] - rmean[idx]) + beta[idx];
    }
    // ---- folded tail: atom_types [768,17], bond_types [2048,5] ----
    if (idx < 768 * 17) {
        int row = idx / 17, c = idx % 17;
        const float* hr = h_l + (size_t)row * 128;
        float s = bat[c];
        #pragma unroll 4
        for (int k = 0; k < 128; ++k) s += hr[k] * Wat[k * 17 + c];
        out_at[idx] = s;
    } else if (idx < 768 * 17 + 2048 * 5) {
        int t2 = idx - 768 * 17;
        int e = t2 / 5, c = t2 % 5;
        const float* hs = h_l + (size_t)esrc[e] * 128;
        const float* hd = h_l + (size_t)edst[e] * 128;
        float s = bbt[c];
        #pragma unroll 4
        for (int k = 0; k < 128; ++k)
            s += hs[k] * Wbt[k * 5 + c] + hd[k] * Wbt[(k + 128) * 5 + c];
        out_bt[t2] = s;
    }
}

// ---------------------------------------------------------------------------
// node_gemm: Lq (BN shift folded) / Pq (scale only), bf16 output
// ---------------------------------------------------------------------------
__global__ __launch_bounds__(256, 2) void node_gemm(
        const float* __restrict__ h_l, const float* __restrict__ h_p,
        const unsigned short* __restrict__ W1T,
        const float* __restrict__ a1v, const float* __restrict__ csv,
        unsigned short* __restrict__ Lq, unsigned short* __restrict__ Pq) {
    const int tid = threadIdx.x, lane = tid & 63, w = tid >> 6;
    const int cGrp = lane & 15, g = lane >> 4;
    const int row0 = blockIdx.x * 64;
    const bool isLig = row0 < 768;
    const float* src = isLig ? (h_l + (size_t)row0 * 128) : (h_p + (size_t)(row0 - 768) * 128);
    unsigned short* dst = isLig ? (Lq + (size_t)row0 * 256) : (Pq + (size_t)(row0 - 768) * 256);
    const int koff = isLig ? 0 : 128;

    f32x4 acc[16];
    #pragma unroll
    for (int fn = 0; fn < 16; ++fn) acc[fn] = (f32x4){0.f, 0.f, 0.f, 0.f};

    #pragma unroll
    for (int fk = 0; fk < 4; ++fk) {
        const float* ap = src + (size_t)(w * 16 + cGrp) * 128 + fk * 32 + g * 8;
        f32x4 qa = *(const f32x4*)ap;
        f32x4 qb = *(const f32x4*)(ap + 4);
        bf16x8 af;
        af[0] = (short)f2bf(qa[0]); af[1] = (short)f2bf(qa[1]);
        af[2] = (short)f2bf(qa[2]); af[3] = (short)f2bf(qa[3]);
        af[4] = (short)f2bf(qb[0]); af[5] = (short)f2bf(qb[1]);
        af[6] = (short)f2bf(qb[2]); af[7] = (short)f2bf(qb[3]);
        #pragma unroll
        for (int fn = 0; fn < 16; ++fn) {
            bf16x8 bf = *(const bf16x8*)(W1T + (fn * 16 + cGrp) * 256 + koff + fk * 32 + g * 8);
            acc[fn] = __builtin_amdgcn_mfma_f32_16x16x32_bf16(af, bf, acc[fn], 0, 0, 0);
        }
    }
    #pragma unroll
    for (int fn = 0; fn < 16; ++fn) {
        int h = fn * 16 + cGrp;
        float s = a1v[h];
        float c0 = isLig ? csv[h] : 0.f;
        #pragma unroll
        for (int rg = 0; rg < 4; ++rg)
            dst[(size_t)(w * 16 + g * 4 + rg) * 256 + h] = f2bf(s * acc[fn][rg] + c0);
    }
}

// ---------------------------------------------------------------------------
// pair_kernel: grid (5120, 3 heads), block 256 (4 waves).
// Tile = 64 rows x 144 cols. Wave = 16 rows x 144 cols (9 frags).
// LDS 36.9 KB -> 4 co-resident blocks/CU.
// ---------------------------------------------------------------------------
__global__ __launch_bounds__(256, 4) void pair_kernel(
        const unsigned short* __restrict__ Lq, const unsigned short* __restrict__ Pq,
        const unsigned char* __restrict__ W2q, const float* __restrict__ b2s,
        const float* __restrict__ lig_pos, const float* __restrict__ prot_pos,
        float* __restrict__ out_pi, float* __restrict__ out_sig, float* __restrict__ out_mu,
        float* __restrict__ out_dist, float* __restrict__ out_pb) {

    __shared__ __align__(16) unsigned char Bs[36864];

    const int tid = threadIdx.x, lane = tid & 63, w = tid >> 6;
    const int c = lane & 15, g = lane >> 4;
    const int head = blockIdx.y;
    const int m0 = blockIdx.x * 64;

    // ---- closed-form pair decode (64-row tile: one batch + ligand run) ----
    unsigned int P = (unsigned int)m0 / 40960u;
    unsigned int r = (unsigned int)m0 % 40960u;
    int b, cl, cp0;
    if (r < 8192u) {            // even batch: 32 lig x 256 prot
        b = 2 * (int)P; cl = 96 * (int)P + (int)(r >> 8); cp0 = 768 * (int)P + (int)(r & 255u);
    } else {                    // odd batch: 64 lig x 512 prot
        unsigned int rr = r - 8192u;
        b = 2 * (int)P + 1; cl = 96 * (int)P + 32 + (int)(rr >> 9);
        cp0 = 768 * (int)P + 256 + (int)(rr & 511u);
    }

    // ---- issue weight staging loads (9 x 16B/thread = 36864 B) ----
    const unsigned char* wsrc = W2q + (size_t)head * 36864;
    u32x4 stg[9];
    #pragma unroll
    for (int i = 0; i < 9; ++i)
        stg[i] = *(const u32x4*)(wsrc + (size_t)(tid + 256 * i) * 16);

    // ---- bias (x16 prescaled) ----
    float bb[9];
    #pragma unroll
    for (int f = 0; f < 9; ++f) bb[f] = b2s[head * 144 + f * 16 + c];

    // ---- X = fp8(elu(Lq+Pq)) in registers (A-fragment layout) ----
    const int row = w * 16 + c;
    const unsigned short* pqp = Pq + (size_t)(cp0 + row) * 256;
    const unsigned short* lqp = Lq + (size_t)cl * 256;
    long Xa[8];
    #pragma unroll
    for (int s = 0; s < 8; ++s) {
        u32x4 pv = *(const u32x4*)(pqp + s * 32 + g * 8);
        u32x4 lv = *(const u32x4*)(lqp + s * 32 + g * 8);
        float y0 = eluf(bfhalf_lo(pv[0]) + bfhalf_lo(lv[0]));
        float y1 = eluf(bfhalf_hi(pv[0]) + bfhalf_hi(lv[0]));
        float y2 = eluf(bfhalf_lo(pv[1]) + bfhalf_lo(lv[1]));
        float y3 = eluf(bfhalf_hi(pv[1]) + bfhalf_hi(lv[1]));
        float y4 = eluf(bfhalf_lo(pv[2]) + bfhalf_lo(lv[2]));
        float y5 = eluf(bfhalf_hi(pv[2]) + bfhalf_hi(lv[2]));
        float y6 = eluf(bfhalf_lo(pv[3]) + bfhalf_lo(lv[3]));
        float y7 = eluf(bfhalf_hi(pv[3]) + bfhalf_hi(lv[3]));
        unsigned int lo = (unsigned int)__builtin_amdgcn_cvt_pk_fp8_f32(y0, y1, 0, false);
        lo = (unsigned int)__builtin_amdgcn_cvt_pk_fp8_f32(y2, y3, (int)lo, true);
        unsigned int hi = (unsigned int)__builtin_amdgcn_cvt_pk_fp8_f32(y4, y5, 0, false);
        hi = (unsigned int)__builtin_amdgcn_cvt_pk_fp8_f32(y6, y7, (int)hi, true);
        Xa[s] = (long)(((unsigned long long)hi << 32) | (unsigned long long)lo);
    }

    // ---- write staged weights to LDS, single barrier ----
    #pragma unroll
    for (int i = 0; i < 9; ++i)
        *(u32x4*)(Bs + (size_t)(tid + 256 * i) * 16) = stg[i];
    __syncthreads();

    // ---- K-loop: 36 conflict-free ds_read_b128 + 72 fp8 MFMA ----
    f32x4 acc[9];
    #pragma unroll
    for (int f = 0; f < 9; ++f) acc[f] = (f32x4){bb[f], bb[f], bb[f], bb[f]};

    #pragma unroll
    for (int sp = 0; sp < 4; ++sp) {
        long xa0 = Xa[2 * sp], xa1 = Xa[2 * sp + 1];
        #pragma unroll
        for (int f = 0; f < 9; ++f) {
            u32x4 bq = *(const u32x4*)(Bs + f * 4096 + sp * 1024 + lane * 16);
            long b0 = (long)(((unsigned long long)bq[1] << 32) | (unsigned long long)bq[0]);
            long b1 = (long)(((unsigned long long)bq[3] << 32) | (unsigned long long)bq[2]);
            acc[f] = __builtin_amdgcn_mfma_f32_16x16x32_fp8_fp8(xa0, b0, acc[f], 0, 0, 0);
            acc[f] = __builtin_amdgcn_mfma_f32_16x16x32_fp8_fp8(xa1, b1, acc[f], 0, 0, 0);
        }
    }

    // ---- de-scale ----
    #pragma unroll
    for (int f = 0; f < 9; ++f)
        #pragma unroll
        for (int q = 0; q < 4; ++q) acc[f][q] *= WDESCALE;

    const bool v8 = (c < 12);   // frag 8 covers cols 128..143, valid < 140

    if (head == 0) {
        // ---- pi: softmax over 140 cols, 16-lane-group local ----
        #pragma unroll
        for (int q = 0; q < 4; ++q) {
            float mx = fmaxf(fmaxf(fmaxf(acc[0][q], acc[1][q]), fmaxf(acc[2][q], acc[3][q])),
                             fmaxf(fmaxf(acc[4][q], acc[5][q]), fmaxf(acc[6][q], acc[7][q])));
            if (v8) mx = fmaxf(mx, acc[8][q]);
            mx = fmaxf(mx, __shfl_xor(mx, 1, 64));
            mx = fmaxf(mx, __shfl_xor(mx, 2, 64));
            mx = fmaxf(mx, __shfl_xor(mx, 4, 64));
            mx = fmaxf(mx, __shfl_xor(mx, 8, 64));
            float e0 = __expf(acc[0][q] - mx), e1 = __expf(acc[1][q] - mx);
            float e2 = __expf(acc[2][q] - mx), e3 = __expf(acc[3][q] - mx);
            float e4 = __expf(acc[4][q] - mx), e5 = __expf(acc[5][q] - mx);
            float e6 = __expf(acc[6][q] - mx), e7 = __expf(acc[7][q] - mx);
            float e8 = v8 ? __expf(acc[8][q] - mx) : 0.f;
            float sm = ((e0 + e1) + (e2 + e3)) + ((e4 + e5) + (e6 + e7)) + e8;
            sm += __shfl_xor(sm, 1, 64);
            sm += __shfl_xor(sm, 2, 64);
            sm += __shfl_xor(sm, 4, 64);
            sm += __shfl_xor(sm, 8, 64);
            float inv = 1.f / sm;
            const int gr = m0 + w * 16 + g * 4 + q;
            float* prow = out_pi + (size_t)gr * 140;
            prow[c]       = e0 * inv;  prow[16 + c]  = e1 * inv;
            prow[32 + c]  = e2 * inv;  prow[48 + c]  = e3 * inv;
            prow[64 + c]  = e4 * inv;  prow[80 + c]  = e5 * inv;
            prow[96 + c]  = e6 * inv;  prow[112 + c] = e7 * inv;
            if (v8) prow[128 + c] = e8 * inv;
        }
    } else if (head == 1) {
        #pragma unroll
        for (int q = 0; q < 4; ++q) {
            const int gr = m0 + w * 16 + g * 4 + q;
            float* srow = out_sig + (size_t)gr * 140;
            srow[c]       = eluf(acc[0][q]) + 1.1f;
            srow[16 + c]  = eluf(acc[1][q]) + 1.1f;
            srow[32 + c]  = eluf(acc[2][q]) + 1.1f;
            srow[48 + c]  = eluf(acc[3][q]) + 1.1f;
            srow[64 + c]  = eluf(acc[4][q]) + 1.1f;
            srow[80 + c]  = eluf(acc[5][q]) + 1.1f;
            srow[96 + c]  = eluf(acc[6][q]) + 1.1f;
            srow[112 + c] = eluf(acc[7][q]) + 1.1f;
            if (v8) srow[128 + c] = eluf(acc[8][q]) + 1.1f;
        }
    } else {
        #pragma unroll
        for (int q = 0; q < 4; ++q) {
            const int gr = m0 + w * 16 + g * 4 + q;
            float* mrow = out_mu + (size_t)gr * 140;
            mrow[c]       = eluf(acc[0][q]) + 1.0f;
            mrow[16 + c]  = eluf(acc[1][q]) + 1.0f;
            mrow[32 + c]  = eluf(acc[2][q]) + 1.0f;
            mrow[48 + c]  = eluf(acc[3][q]) + 1.0f;
            mrow[64 + c]  = eluf(acc[4][q]) + 1.0f;
            mrow[80 + c]  = eluf(acc[5][q]) + 1.0f;
            mrow[96 + c]  = eluf(acc[6][q]) + 1.0f;
            mrow[112 + c] = eluf(acc[7][q]) + 1.0f;
            if (v8) mrow[128 + c] = eluf(acc[8][q]) + 1.0f;
        }
        // ---- dist + pb (head-2 blocks only) ----
        float lx = lig_pos[cl * 3 + 0];
        float ly = lig_pos[cl * 3 + 1];
        float lz = lig_pos[cl * 3 + 2];
        for (int idx = tid; idx < 64 * 14; idx += 256) {
            int rw = idx / 14, a = idx - rw * 14;
            const float* pp = prot_pos + (size_t)(cp0 + rw) * 42 + a * 3;
            float dx = lx - pp[0], dy = ly - pp[1], dz = lz - pp[2];
            out_dist[(size_t)(m0 + rw) * 14 + a] = sqrtf(dx * dx + dy * dy + dz * dz);
        }
        if (tid < 64) out_pb[m0 + tid] = (float)b;
    }
}

// ---------------------------------------------------------------------------
extern "C" void kernel_launch(void* const* d_in, const int* in_sizes, int n_in,
                              void* d_out, int out_size, void* d_ws, size_t ws_size,
                              hipStream_t stream) {
    const float* h_l      = (const float*)d_in[0];
    const float* h_p      = (const float*)d_in[1];
    const float* lig_pos  = (const float*)d_in[2];
    const float* prot_pos = (const float*)d_in[3];
    const int*   esrc     = (const int*)d_in[4];
    const int*   edst     = (const int*)d_in[5];
    const float* W1    = (const float*)d_in[12];
    const float* b1    = (const float*)d_in[13];
    const float* gamma = (const float*)d_in[14];
    const float* beta  = (const float*)d_in[15];
    const float* rmean = (const float*)d_in[16];
    const float* rvar  = (const float*)d_in[17];
    const float* Wpi   = (const float*)d_in[18];
    const float* bpi   = (const float*)d_in[19];
    const float* Wsig  = (const float*)d_in[20];
    const float* bsig  = (const float*)d_in[21];
    const float* Wmu   = (const float*)d_in[22];
    const float* bmu   = (const float*)d_in[23];
    const float* Wat   = (const float*)d_in[24];
    const float* bat   = (const float*)d_in[25];
    const float* Wbt   = (const float*)d_in[26];
    const float* bbt   = (const float*)d_in[27];

    char* ws = (char*)d_ws;
    unsigned short* W1T = (unsigned short*)(ws + 0);
    unsigned char*  W2q = (unsigned char*)(ws + 131072);
    float*          b2s = (float*)(ws + 241664);
    float*          a1v = (float*)(ws + 243392);
    float*          csv = (float*)(ws + 244416);
    unsigned short* Lq  = (unsigned short*)(ws + 245440);
    unsigned short* Pq  = (unsigned short*)(ws + 638656);

    float* out = (float*)d_out;
    const size_t M = M_TOT;
    float* out_pi   = out;
    float* out_sig  = out + M * 140;
    float* out_mu   = out + 2 * M * 140;
    float* out_dist = out + 3 * M * 140;
    float* out_at   = out + 3 * M * 140 + M * 14;
    float* out_bt   = out_at + 768 * 17;
    float* out_pb   = out_bt + 2048 * 5;

    hipLaunchKernelGGL(prep_weights, dim3(432), dim3(256), 0, stream,
                       W1, b1, gamma, beta, rmean, rvar,
                       Wpi, bpi, Wsig, bsig, Wmu, bmu,
                       h_l, esrc, edst, Wat, bat, Wbt, bbt,
                       W1T, W2q, b2s, a1v, csv, out_at, out_bt);

    hipLaunchKernelGGL(node_gemm, dim3((768 + 6144) / 64), dim3(256), 0, stream,
                       h_l, h_p, W1T, a1v, csv, Lq, Pq);

    hipLaunchKernelGGL(pair_kernel, dim3(M_TOT / 64, 3), dim3(256), 0, stream,
                       Lq, Pq, W2q, b2s, lig_pos, prot_pos,
                       out_pi, out_sig, out_mu, out_dist, out_pb);
}